// Round 1
// baseline (2251.987 us; speedup 1.0000x reference)
//
#include <hip/hip_runtime.h>
#include <hip/hip_bf16.h>

// Problem constants: B=4, M=2048, D=1024, H=16, K=V=64
#define B_  4
#define M_  2048
#define D_  1024
#define H_  16

// Workspace layout (floats):
//   Qw  [B*H][M][64]   8,388,608
//   Kw  [B*H][M][64]   8,388,608
//   Vw  [B*H][M][64]   8,388,608
//   Ow  [B][M][H][64]  8,388,608   (O transposed to [bm][hv] for final GEMM)
//   Wt  [1024][1024]   1,048,576   (P_o transposed: Wt[h*64+v][d] = P_o[h][d][v])
// total = 34,603,008 floats = 138.4 MB

__device__ __forceinline__ void fma_row(float (&acc)[4], float a, const float4 b) {
  acc[0] = fmaf(a, b.x, acc[0]);
  acc[1] = fmaf(a, b.y, acc[1]);
  acc[2] = fmaf(a, b.z, acc[2]);
  acc[3] = fmaf(a, b.w, acc[3]);
}

// ---------------------------------------------------------------------------
// Generic 64x64 output tile fp32 GEMM: C[64][64] = A[64][Kd] * B[Kd][64]
// block = 256 threads, each thread computes a 4x4 micro-tile.
// ---------------------------------------------------------------------------
__device__ __forceinline__ void gemm_tile_64x64(
    const float* __restrict__ A, int lda,
    const float* __restrict__ Bp, int ldb,
    int Kd,
    float* __restrict__ C, int ldc)
{
  __shared__ __align__(16) float As[64][20];  // pitch 20 floats = 80B (16B-aligned rows)
  __shared__ __align__(16) float Bs[16][64];
  const int t  = threadIdx.x;
  const int tx = t & 15, ty = t >> 4;
  const int ar = t >> 2,  ac = (t & 3) << 2;   // A tile load: [64][16]
  const int br = t >> 4,  bc = (t & 15) << 2;  // B tile load: [16][64]
  float acc[4][4] = {};
  for (int d0 = 0; d0 < Kd; d0 += 16) {
    float4 av = *(const float4*)(A  + (size_t)ar * lda + d0 + ac);
    float4 bv = *(const float4*)(Bp + (size_t)(d0 + br) * ldb + bc);
    __syncthreads();   // previous iteration's compute done before overwrite
    *(float4*)&As[ar][ac] = av;
    *(float4*)&Bs[br][bc] = bv;
    __syncthreads();
#pragma unroll
    for (int k4 = 0; k4 < 16; k4 += 4) {
      float4 a0 = *(const float4*)&As[ty * 4 + 0][k4];
      float4 a1 = *(const float4*)&As[ty * 4 + 1][k4];
      float4 a2 = *(const float4*)&As[ty * 4 + 2][k4];
      float4 a3 = *(const float4*)&As[ty * 4 + 3][k4];
      float4 b0 = *(const float4*)&Bs[k4 + 0][tx * 4];
      float4 b1 = *(const float4*)&Bs[k4 + 1][tx * 4];
      float4 b2 = *(const float4*)&Bs[k4 + 2][tx * 4];
      float4 b3 = *(const float4*)&Bs[k4 + 3][tx * 4];
      fma_row(acc[0], a0.x, b0); fma_row(acc[0], a0.y, b1); fma_row(acc[0], a0.z, b2); fma_row(acc[0], a0.w, b3);
      fma_row(acc[1], a1.x, b0); fma_row(acc[1], a1.y, b1); fma_row(acc[1], a1.z, b2); fma_row(acc[1], a1.w, b3);
      fma_row(acc[2], a2.x, b0); fma_row(acc[2], a2.y, b1); fma_row(acc[2], a2.z, b2); fma_row(acc[2], a2.w, b3);
      fma_row(acc[3], a3.x, b0); fma_row(acc[3], a3.y, b1); fma_row(acc[3], a3.z, b2); fma_row(acc[3], a3.w, b3);
    }
  }
#pragma unroll
  for (int i = 0; i < 4; ++i) {
    float4 cv = make_float4(acc[i][0], acc[i][1], acc[i][2], acc[i][3]);
    *(float4*)(C + (size_t)(ty * 4 + i) * ldc + tx * 4) = cv;
  }
}

// ---------------------------------------------------------------------------
// QKV projection: for each (b,h,which): out[bh][m0..m0+63][0..63] =
//   x[b][m0..][:] @ P_which[h][:][:]
// grid = (M/64, B*H, 3)
// ---------------------------------------------------------------------------
__global__ __launch_bounds__(256) void qkv_proj_kernel(
    const float* __restrict__ x,
    const float* __restrict__ Pq, const float* __restrict__ Pk, const float* __restrict__ Pv,
    float* __restrict__ Qw, float* __restrict__ Kw, float* __restrict__ Vw)
{
  const int bh = blockIdx.y;
  const int b = bh >> 4;              // H_ == 16
  const int h = bh & 15;
  const int m0 = blockIdx.x * 64;
  const float* P; float* out;
  if (blockIdx.z == 0)      { P = Pq; out = Qw; }
  else if (blockIdx.z == 1) { P = Pk; out = Kw; }
  else                      { P = Pv; out = Vw; }
  gemm_tile_64x64(x + ((size_t)b * M_ + m0) * D_, D_,
                  P + (size_t)h * D_ * 64, 64,
                  D_,
                  out + ((size_t)bh * M_ + m0) * 64, 64);
}

// ---------------------------------------------------------------------------
// Flash attention (causal): one block per (q-tile of 64 rows, b, h).
// Online softmax, 4x4 micro-tiles, K stored transposed in LDS.
// Writes O in [b][m][h][v] layout for the final GEMM.
// ---------------------------------------------------------------------------
__global__ __launch_bounds__(256) void flash_attn_kernel(
    const float* __restrict__ Qg, const float* __restrict__ Kg,
    const float* __restrict__ Vg, float* __restrict__ O2)
{
  __shared__ __align__(16) float Qs [64][68];  // pitch 68 floats = 272B, 16B-aligned rows
  __shared__ __align__(16) float KsT[64][68];  // KsT[k][n] = K[n][k]
  __shared__ __align__(16) float Vs [64][68];
  __shared__ __align__(16) float Ps [64][68];

  const int bh = blockIdx.y;
  const int b = bh >> 4, h = bh & 15;
  const int i0 = ((int)gridDim.x - 1 - (int)blockIdx.x) * 64;  // heavy tiles first
  const float* Qp = Qg + ((size_t)bh * M_ + i0) * 64;
  const float* Kp = Kg + (size_t)bh * M_ * 64;
  const float* Vp = Vg + (size_t)bh * M_ * 64;

  const int t  = threadIdx.x;
  const int tx = t & 15, ty = t >> 4;
  const int lr = t >> 2, lc0 = (t & 3) << 4;   // tile loader: row, col-base (16 cols/thread)

  // load Q tile, pre-scaled by 1/sqrt(64)
#pragma unroll
  for (int j = 0; j < 4; ++j) {
    float4 v = *(const float4*)(Qp + (size_t)lr * 64 + lc0 + j * 4);
    v.x *= 0.125f; v.y *= 0.125f; v.z *= 0.125f; v.w *= 0.125f;
    *(float4*)&Qs[lr][lc0 + j * 4] = v;
  }

  float m_run[4], l_run[4], o_acc[4][4];
#pragma unroll
  for (int i = 0; i < 4; ++i) {
    m_run[i] = -3.0e38f; l_run[i] = 0.f;
#pragma unroll
    for (int j = 0; j < 4; ++j) o_acc[i][j] = 0.f;
  }

  for (int j0 = 0; j0 <= i0; j0 += 64) {
    __syncthreads();   // prior iteration done reading KsT/Vs/Ps (Q store also covered, iter 0)
    // load K (transposed into LDS) and V tiles
#pragma unroll
    for (int j = 0; j < 4; ++j) {
      float4 kv = *(const float4*)(Kp + (size_t)(j0 + lr) * 64 + lc0 + j * 4);
      KsT[lc0 + j * 4 + 0][lr] = kv.x;
      KsT[lc0 + j * 4 + 1][lr] = kv.y;
      KsT[lc0 + j * 4 + 2][lr] = kv.z;
      KsT[lc0 + j * 4 + 3][lr] = kv.w;
      float4 vv = *(const float4*)(Vp + (size_t)(j0 + lr) * 64 + lc0 + j * 4);
      *(float4*)&Vs[lr][lc0 + j * 4] = vv;
    }
    __syncthreads();

    // S = (Q*scale) K^T : thread owns rows ty*4+i, cols tx*4+j
    float s[4][4] = {};
#pragma unroll
    for (int k4 = 0; k4 < 64; k4 += 4) {
      float4 q0 = *(const float4*)&Qs[ty * 4 + 0][k4];
      float4 q1 = *(const float4*)&Qs[ty * 4 + 1][k4];
      float4 q2 = *(const float4*)&Qs[ty * 4 + 2][k4];
      float4 q3 = *(const float4*)&Qs[ty * 4 + 3][k4];
      float4 b0 = *(const float4*)&KsT[k4 + 0][tx * 4];
      float4 b1 = *(const float4*)&KsT[k4 + 1][tx * 4];
      float4 b2 = *(const float4*)&KsT[k4 + 2][tx * 4];
      float4 b3 = *(const float4*)&KsT[k4 + 3][tx * 4];
      fma_row(s[0], q0.x, b0); fma_row(s[0], q0.y, b1); fma_row(s[0], q0.z, b2); fma_row(s[0], q0.w, b3);
      fma_row(s[1], q1.x, b0); fma_row(s[1], q1.y, b1); fma_row(s[1], q1.z, b2); fma_row(s[1], q1.w, b3);
      fma_row(s[2], q2.x, b0); fma_row(s[2], q2.y, b1); fma_row(s[2], q2.z, b2); fma_row(s[2], q2.w, b3);
      fma_row(s[3], q3.x, b0); fma_row(s[3], q3.y, b1); fma_row(s[3], q3.z, b2); fma_row(s[3], q3.w, b3);
    }

    if (j0 == i0) {  // diagonal block: mask keys n > q
#pragma unroll
      for (int i = 0; i < 4; ++i)
#pragma unroll
        for (int j = 0; j < 4; ++j)
          if (tx * 4 + j > ty * 4 + i) s[i][j] = -3.0e38f;
    }

    // online softmax update (row groups = 16 contiguous lanes)
#pragma unroll
    for (int i = 0; i < 4; ++i) {
      float rm = fmaxf(fmaxf(s[i][0], s[i][1]), fmaxf(s[i][2], s[i][3]));
      rm = fmaxf(rm, __shfl_xor(rm, 1));
      rm = fmaxf(rm, __shfl_xor(rm, 2));
      rm = fmaxf(rm, __shfl_xor(rm, 4));
      rm = fmaxf(rm, __shfl_xor(rm, 8));
      const float mnew  = fmaxf(m_run[i], rm);
      const float alpha = __expf(m_run[i] - mnew);
      m_run[i] = mnew;
      float rs = 0.f;
#pragma unroll
      for (int j = 0; j < 4; ++j) {
        const float p = __expf(s[i][j] - mnew);
        Ps[ty * 4 + i][tx * 4 + j] = p;
        rs += p;
      }
      rs += __shfl_xor(rs, 1);
      rs += __shfl_xor(rs, 2);
      rs += __shfl_xor(rs, 4);
      rs += __shfl_xor(rs, 8);
      l_run[i] = l_run[i] * alpha + rs;
#pragma unroll
      for (int j = 0; j < 4; ++j) o_acc[i][j] *= alpha;
    }
    __syncthreads();   // Ps visible to all

    // O += P * V
#pragma unroll
    for (int k4 = 0; k4 < 64; k4 += 4) {
      float4 p0 = *(const float4*)&Ps[ty * 4 + 0][k4];
      float4 p1 = *(const float4*)&Ps[ty * 4 + 1][k4];
      float4 p2 = *(const float4*)&Ps[ty * 4 + 2][k4];
      float4 p3 = *(const float4*)&Ps[ty * 4 + 3][k4];
      float4 v0 = *(const float4*)&Vs[k4 + 0][tx * 4];
      float4 v1 = *(const float4*)&Vs[k4 + 1][tx * 4];
      float4 v2 = *(const float4*)&Vs[k4 + 2][tx * 4];
      float4 v3 = *(const float4*)&Vs[k4 + 3][tx * 4];
      fma_row(o_acc[0], p0.x, v0); fma_row(o_acc[0], p0.y, v1); fma_row(o_acc[0], p0.z, v2); fma_row(o_acc[0], p0.w, v3);
      fma_row(o_acc[1], p1.x, v0); fma_row(o_acc[1], p1.y, v1); fma_row(o_acc[1], p1.z, v2); fma_row(o_acc[1], p1.w, v3);
      fma_row(o_acc[2], p2.x, v0); fma_row(o_acc[2], p2.y, v1); fma_row(o_acc[2], p2.z, v2); fma_row(o_acc[2], p2.w, v3);
      fma_row(o_acc[3], p3.x, v0); fma_row(o_acc[3], p3.y, v1); fma_row(o_acc[3], p3.z, v2); fma_row(o_acc[3], p3.w, v3);
    }
  }

  // epilogue: O2[b][m][h][v] = o_acc / l
#pragma unroll
  for (int i = 0; i < 4; ++i) {
    const float inv = 1.0f / l_run[i];
    const int row = i0 + ty * 4 + i;
    float4 o = make_float4(o_acc[i][0] * inv, o_acc[i][1] * inv,
                           o_acc[i][2] * inv, o_acc[i][3] * inv);
    *(float4*)(O2 + (((size_t)b * M_ + row) * H_ + h) * 64 + tx * 4) = o;
  }
}

// ---------------------------------------------------------------------------
// Wt[h*64+v][d] = P_o[h][d][v]
// ---------------------------------------------------------------------------
__global__ __launch_bounds__(256) void transpose_po_kernel(
    const float* __restrict__ Po, float* __restrict__ Wt)
{
  const int idx = blockIdx.x * 256 + threadIdx.x;  // idx = hv*1024 + d
  const int d  = idx & 1023;
  const int hv = idx >> 10;
  const int h = hv >> 6, v = hv & 63;
  Wt[idx] = Po[((size_t)h * D_ + d) * 64 + v];
}

// ---------------------------------------------------------------------------
// y[bm][d] = O2[bm][hv] * Wt[hv][d]   (8192 x 1024 x 1024)
// ---------------------------------------------------------------------------
__global__ __launch_bounds__(256) void out_proj_kernel(
    const float* __restrict__ O2, const float* __restrict__ Wt, float* __restrict__ y)
{
  const int m0 = blockIdx.x * 64;
  const int n0 = blockIdx.y * 64;
  gemm_tile_64x64(O2 + (size_t)m0 * 1024, 1024,
                  Wt + n0, 1024,
                  1024,
                  y + (size_t)m0 * 1024 + n0, 1024);
}

// ---------------------------------------------------------------------------
extern "C" void kernel_launch(void* const* d_in, const int* in_sizes, int n_in,
                              void* d_out, int out_size, void* d_ws, size_t ws_size,
                              hipStream_t stream) {
  const float* x  = (const float*)d_in[0];
  const float* Pq = (const float*)d_in[1];
  const float* Pk = (const float*)d_in[2];
  const float* Pv = (const float*)d_in[3];
  const float* Po = (const float*)d_in[4];
  float* y = (float*)d_out;

  float* ws = (float*)d_ws;
  const size_t SZ = (size_t)B_ * H_ * M_ * 64;   // 8,388,608 floats per tensor
  float* Qw = ws;
  float* Kw = Qw + SZ;
  float* Vw = Kw + SZ;
  float* Ow = Vw + SZ;
  float* Wt = Ow + SZ;    // 1024*1024 floats

  transpose_po_kernel<<<4096, 256, 0, stream>>>(Po, Wt);
  qkv_proj_kernel<<<dim3(M_ / 64, B_ * H_, 3), 256, 0, stream>>>(x, Pq, Pk, Pv, Qw, Kw, Vw);
  flash_attn_kernel<<<dim3(M_ / 64, B_ * H_), 256, 0, stream>>>(Qw, Kw, Vw, Ow);
  out_proj_kernel<<<dim3((B_ * M_) / 64, D_ / 64), 256, 0, stream>>>(Ow, Wt, y);
}

// Round 2
// 515.585 us; speedup vs baseline: 4.3678x; 4.3678x over previous
//
#include <hip/hip_runtime.h>
#include <hip/hip_bf16.h>

// B=4, M=2048, D=1024, H=16, K=V=64
#define B_  4
#define M_  2048
#define D_  1024
#define H_  16
#define BH_ 64

typedef __attribute__((ext_vector_type(8))) short bf16x8;
typedef __attribute__((ext_vector_type(4))) float f32x4;
typedef __attribute__((ext_vector_type(4))) unsigned short u16x4;

#define MFMA(a, b, c) __builtin_amdgcn_mfma_f32_16x16x32_bf16((a), (b), (c), 0, 0, 0)

__device__ __forceinline__ unsigned short f2b(float f) {
  union { float f; unsigned u; } v; v.f = f;
  unsigned r = v.u + 0x7FFF + ((v.u >> 16) & 1);   // RNE
  return (unsigned short)(r >> 16);
}

// XOR swizzle within a [rows][64-bf16] tile (128B rows): spreads the 8 16B
// slots of a row across banks by row&7. Applied to BOTH stage-source and reads.
__device__ __forceinline__ int swzb(int byte) {
  return byte ^ (((byte >> 7) & 7) << 4);
}

#define GLOAD16(gsrc, ldst)                                                     \
  __builtin_amdgcn_global_load_lds(                                             \
      (const __attribute__((address_space(1))) void*)(gsrc),                    \
      (__attribute__((address_space(3))) void*)(ldst), 16, 0, 0)

// ---------------------------------------------------------------------------
// Conversions
// ---------------------------------------------------------------------------
__global__ __launch_bounds__(256) void convert_x_kernel(
    const float* __restrict__ x, short* __restrict__ xb) {
  const size_t i = ((size_t)blockIdx.x * 256 + threadIdx.x) * 8;
  float4 a = *(const float4*)(x + i);
  float4 b = *(const float4*)(x + i + 4);
  bf16x8 o;
  o[0] = (short)f2b(a.x); o[1] = (short)f2b(a.y); o[2] = (short)f2b(a.z); o[3] = (short)f2b(a.w);
  o[4] = (short)f2b(b.x); o[5] = (short)f2b(b.y); o[6] = (short)f2b(b.z); o[7] = (short)f2b(b.w);
  *(bf16x8*)(xb + i) = o;
}

// Wt[n][d], n = which*1024 + h*64 + kc ; Wt[n][d] = P_which[h][d][kc]
__global__ __launch_bounds__(256) void convert_w_kernel(
    const float* __restrict__ Pq, const float* __restrict__ Pk,
    const float* __restrict__ Pv, short* __restrict__ Wt) {
  const int idx = blockIdx.x * 256 + threadIdx.x;   // n*256 + d/4
  const int n = idx >> 8, d0 = (idx & 255) * 4;
  const int which = n >> 10, h = (n >> 6) & 15, kc = n & 63;
  const float* P = (which == 0) ? Pq : (which == 1) ? Pk : Pv;
  const float* p = P + ((size_t)h * D_ + d0) * 64 + kc;
  u16x4 o;
  o[0] = f2b(p[0]); o[1] = f2b(p[64]); o[2] = f2b(p[128]); o[3] = f2b(p[192]);
  *(u16x4*)(Wt + (size_t)n * D_ + d0) = o;
}

// Wo[d][h*64+v] = P_o[h][d][v]
__global__ __launch_bounds__(256) void convert_wo_kernel(
    const float* __restrict__ Po, short* __restrict__ Wo) {
  const int idx = blockIdx.x * 256 + threadIdx.x;   // d*256 + hv/4
  const int d = idx >> 8, hv0 = (idx & 255) * 4;
  const int h = hv0 >> 6, v = hv0 & 63;
  float4 a = *(const float4*)(Po + ((size_t)h * D_ + d) * 64 + v);
  u16x4 o;
  o[0] = f2b(a.x); o[1] = f2b(a.y); o[2] = f2b(a.z); o[3] = f2b(a.w);
  *(u16x4*)(Wo + (size_t)d * 1024 + hv0) = o;
}

// ---------------------------------------------------------------------------
// QKV projection GEMM: C[8192][3072] = xb[8192][1024] @ Wt[3072][1024]^T
// 128x128 tile, BK=64, 4 waves (2x2), each wave 64x64 via 16x16x32 bf16 MFMA.
// Epilogue scatters into Qw/Kw [bh][m][64] and Vt [bh][v][m]; Q scaled 1/8.
// ---------------------------------------------------------------------------
__global__ __launch_bounds__(256) void qkv_gemm_kernel(
    const short* __restrict__ xb, const short* __restrict__ Wt,
    short* __restrict__ Qw, short* __restrict__ Kw, short* __restrict__ Vt) {
  __shared__ short As[128 * 64];
  __shared__ short Bs[128 * 64];
  int bid = blockIdx.x;
  bid = (bid & 7) * 192 + (bid >> 3);            // XCD swizzle (1536 % 8 == 0)
  const int mt = bid & 63, nt = bid >> 6;
  const int m0 = mt * 128, n0 = nt * 128;
  const int t = threadIdx.x, lane = t & 63, w = t >> 6;
  const int wr = (w >> 1) * 64, wc = (w & 1) * 64;
  const int lrow = lane & 15, lgrp = lane >> 4;

  f32x4 acc[4][4] = {};
  const char* Agc = (const char*)xb + (size_t)m0 * D_ * 2;
  const char* Bgc = (const char*)Wt + (size_t)n0 * D_ * 2;

  for (int d0 = 0; d0 < D_; d0 += 64) {
    __syncthreads();
#pragma unroll
    for (int i = 0; i < 4; ++i) {
      const int L = i * 4096 + t * 16;
      const int row = L >> 7;
      const int cb = (L & 127) ^ ((row & 7) << 4);
      GLOAD16(Agc + ((size_t)row * D_ + d0) * 2 + cb, (char*)As + i * 4096 + w * 1024);
      GLOAD16(Bgc + ((size_t)row * D_ + d0) * 2 + cb, (char*)Bs + i * 4096 + w * 1024);
    }
    __syncthreads();
#pragma unroll
    for (int ks = 0; ks < 2; ++ks) {
      bf16x8 a[4], b[4];
      const int cb = ks * 64 + lgrp * 16;
#pragma unroll
      for (int f = 0; f < 4; ++f) {
        a[f] = *(const bf16x8*)((const char*)As + swzb((wr + f * 16 + lrow) * 128 + cb));
        b[f] = *(const bf16x8*)((const char*)Bs + swzb((wc + f * 16 + lrow) * 128 + cb));
      }
#pragma unroll
      for (int mf = 0; mf < 4; ++mf)
#pragma unroll
        for (int nf = 0; nf < 4; ++nf)
          acc[mf][nf] = MFMA(a[mf], b[nf], acc[mf][nf]);
    }
  }

#pragma unroll
  for (int nf = 0; nf < 4; ++nf) {
    const int n = n0 + wc + nf * 16 + lrow;
    const int which = n >> 10, h = (n >> 6) & 15, kc = n & 63;
#pragma unroll
    for (int mf = 0; mf < 4; ++mf) {
      const int row0 = m0 + wr + mf * 16 + lgrp * 4;
      const int b = row0 >> 11, mm = row0 & 2047;
      const int bh = b * 16 + h;
      if (which == 2) {
        u16x4 o;
        o[0] = f2b(acc[mf][nf][0]); o[1] = f2b(acc[mf][nf][1]);
        o[2] = f2b(acc[mf][nf][2]); o[3] = f2b(acc[mf][nf][3]);
        *(u16x4*)(Vt + ((size_t)bh * 64 + kc) * M_ + mm) = o;
      } else {
        short* outp = (which == 0 ? Qw : Kw) + ((size_t)bh * M_ + mm) * 64 + kc;
        const float scale = (which == 0) ? 0.125f : 1.0f;
#pragma unroll
        for (int r = 0; r < 4; ++r)
          outp[(size_t)r * 64] = (short)f2b(acc[mf][nf][r] * scale);
      }
    }
  }
}

// ---------------------------------------------------------------------------
// Flash attention, bf16 MFMA. Block = 4 waves x 64 q-rows = 256 q-rows.
// KV tile = 64. Q pre-scaled. Per-wave causal skip; mask only at j0 == qw.
// ---------------------------------------------------------------------------
__global__ __launch_bounds__(256) void attn_kernel(
    const short* __restrict__ Qw, const short* __restrict__ Kw,
    const short* __restrict__ Vt, short* __restrict__ O2) {
  __shared__ short Ks[64 * 64];
  __shared__ short Vs[64 * 64];
  __shared__ short Ps[4][64 * 64];

  int bid = blockIdx.x;                     // 512 blocks
  bid = (bid & 7) * 64 + (bid >> 3);        // XCD swizzle: 8 bh per XCD (KV ~ L2)
  const int bh = bid >> 3, qi = bid & 7;
  const int q0 = (7 - qi) * 256;            // heavy-first
  const int t = threadIdx.x, lane = t & 63, w = t >> 6;
  const int qw = q0 + w * 64;
  const int lrow = lane & 15, lgrp = lane >> 4;

  // Q fragments in registers (reused all iterations)
  bf16x8 qa[4][2];
#pragma unroll
  for (int mf = 0; mf < 4; ++mf)
#pragma unroll
    for (int ks = 0; ks < 2; ++ks)
      qa[mf][ks] = *(const bf16x8*)(Qw + ((size_t)bh * M_ + qw + mf * 16 + lrow) * 64 + ks * 32 + lgrp * 8);

  f32x4 o[4][4] = {};
  float mrun[4][4], lrun[4][4];
#pragma unroll
  for (int mf = 0; mf < 4; ++mf)
#pragma unroll
    for (int r = 0; r < 4; ++r) { mrun[mf][r] = -3.0e38f; lrun[mf][r] = 0.f; }

  const char* Kg = (const char*)Kw + (size_t)bh * M_ * 64 * 2;
  const char* Vg = (const char*)Vt + (size_t)bh * 64 * M_ * 2;

  for (int j0 = 0; j0 < q0 + 256; j0 += 64) {
    __syncthreads();                         // all waves done reading prev tiles
#pragma unroll
    for (int i = 0; i < 2; ++i) {
      const int L = i * 4096 + t * 16;
      const int row = L >> 7;
      const int cb = (L & 127) ^ ((row & 7) << 4);
      GLOAD16(Kg + (size_t)(j0 + row) * 128 + cb, (char*)Ks + i * 4096 + w * 1024);
      GLOAD16(Vg + (size_t)row * 4096 + (size_t)j0 * 2 + cb, (char*)Vs + i * 4096 + w * 1024);
    }
    __syncthreads();                         // staged (sync drains vmcnt)
    if (j0 > qw) continue;                   // this wave fully masked for this tile

    // S = Q K^T (Q pre-scaled by 1/8)
    f32x4 s[4][4] = {};
#pragma unroll
    for (int ks = 0; ks < 2; ++ks) {
      bf16x8 kb[4];
      const int cb = ks * 64 + lgrp * 16;
#pragma unroll
      for (int nf = 0; nf < 4; ++nf)
        kb[nf] = *(const bf16x8*)((const char*)Ks + swzb((nf * 16 + lrow) * 128 + cb));
#pragma unroll
      for (int mf = 0; mf < 4; ++mf)
#pragma unroll
        for (int nf = 0; nf < 4; ++nf)
          s[mf][nf] = MFMA(qa[mf][ks], kb[nf], s[mf][nf]);
    }

    if (j0 == qw) {                          // diagonal tile: mask key > q
#pragma unroll
      for (int mf = 0; mf < 4; ++mf)
#pragma unroll
        for (int nf = 0; nf < 4; ++nf)
#pragma unroll
          for (int r = 0; r < 4; ++r)
            if (nf * 16 + lrow > mf * 16 + lgrp * 4 + r) s[mf][nf][r] = -3.0e38f;
    }

    // online softmax (row group = 16 lanes)
#pragma unroll
    for (int mf = 0; mf < 4; ++mf) {
#pragma unroll
      for (int r = 0; r < 4; ++r) {
        float rm = fmaxf(fmaxf(s[mf][0][r], s[mf][1][r]), fmaxf(s[mf][2][r], s[mf][3][r]));
        rm = fmaxf(rm, __shfl_xor(rm, 1));
        rm = fmaxf(rm, __shfl_xor(rm, 2));
        rm = fmaxf(rm, __shfl_xor(rm, 4));
        rm = fmaxf(rm, __shfl_xor(rm, 8));
        const float mold = mrun[mf][r];
        const float mnew = fmaxf(mold, rm);
        mrun[mf][r] = mnew;
        const float alpha = __expf(mold - mnew);
        float rs = 0.f;
#pragma unroll
        for (int nf = 0; nf < 4; ++nf) {
          const float p = __expf(s[mf][nf][r] - mnew);
          s[mf][nf][r] = p;
          rs += p;
        }
        rs += __shfl_xor(rs, 1);
        rs += __shfl_xor(rs, 2);
        rs += __shfl_xor(rs, 4);
        rs += __shfl_xor(rs, 8);
        lrun[mf][r] = lrun[mf][r] * alpha + rs;
#pragma unroll
        for (int nf = 0; nf < 4; ++nf) o[mf][nf][r] *= alpha;
      }
    }

    // P (bf16) -> per-wave LDS region, swizzled
#pragma unroll
    for (int mf = 0; mf < 4; ++mf)
#pragma unroll
      for (int nf = 0; nf < 4; ++nf)
#pragma unroll
        for (int r = 0; r < 4; ++r) {
          const int row = mf * 16 + lgrp * 4 + r, col = nf * 16 + lrow;
          *(short*)((char*)Ps[w] + swzb(row * 128 + col * 2)) = (short)f2b(s[mf][nf][r]);
        }

    // O += P V   (same-wave LDS ops are in-order; compiler inserts lgkmcnt)
#pragma unroll
    for (int ks = 0; ks < 2; ++ks) {
      bf16x8 pa[4], vb[4];
      const int cb = ks * 64 + lgrp * 16;
#pragma unroll
      for (int mf = 0; mf < 4; ++mf)
        pa[mf] = *(const bf16x8*)((const char*)Ps[w] + swzb((mf * 16 + lrow) * 128 + cb));
#pragma unroll
      for (int nf = 0; nf < 4; ++nf)
        vb[nf] = *(const bf16x8*)((const char*)Vs + swzb((nf * 16 + lrow) * 128 + cb));
#pragma unroll
      for (int mf = 0; mf < 4; ++mf)
#pragma unroll
        for (int nf = 0; nf < 4; ++nf)
          o[mf][nf] = MFMA(pa[mf], vb[nf], o[mf][nf]);
    }
  }

  // epilogue: O2[b][m][h*64+v] = o / l
  const int b = bh >> 4, h = bh & 15;
#pragma unroll
  for (int mf = 0; mf < 4; ++mf)
#pragma unroll
    for (int r = 0; r < 4; ++r) {
      const float inv = 1.0f / lrun[mf][r];
      const int row = qw + mf * 16 + lgrp * 4 + r;
#pragma unroll
      for (int nf = 0; nf < 4; ++nf) {
        const int col = nf * 16 + lrow;
        O2[((size_t)b * M_ + row) * 1024 + h * 64 + col] = (short)f2b(o[mf][nf][r] * inv);
      }
    }
}

// ---------------------------------------------------------------------------
// Output projection: y[8192][1024] = O2[8192][1024](bf16) @ Wo[1024][1024]^T
// ---------------------------------------------------------------------------
__global__ __launch_bounds__(256) void out_gemm_kernel(
    const short* __restrict__ O2, const short* __restrict__ Wo,
    float* __restrict__ y) {
  __shared__ short As[128 * 64];
  __shared__ short Bs[128 * 64];
  int bid = blockIdx.x;
  bid = (bid & 7) * 64 + (bid >> 3);        // XCD swizzle (512 % 8 == 0)
  const int mt = bid & 63, nt = bid >> 6;
  const int m0 = mt * 128, n0 = nt * 128;
  const int t = threadIdx.x, lane = t & 63, w = t >> 6;
  const int wr = (w >> 1) * 64, wc = (w & 1) * 64;
  const int lrow = lane & 15, lgrp = lane >> 4;

  f32x4 acc[4][4] = {};
  const char* Agc = (const char*)O2 + (size_t)m0 * 1024 * 2;
  const char* Bgc = (const char*)Wo + (size_t)n0 * 1024 * 2;

  for (int d0 = 0; d0 < 1024; d0 += 64) {
    __syncthreads();
#pragma unroll
    for (int i = 0; i < 4; ++i) {
      const int L = i * 4096 + t * 16;
      const int row = L >> 7;
      const int cb = (L & 127) ^ ((row & 7) << 4);
      GLOAD16(Agc + ((size_t)row * 1024 + d0) * 2 + cb, (char*)As + i * 4096 + w * 1024);
      GLOAD16(Bgc + ((size_t)row * 1024 + d0) * 2 + cb, (char*)Bs + i * 4096 + w * 1024);
    }
    __syncthreads();
#pragma unroll
    for (int ks = 0; ks < 2; ++ks) {
      bf16x8 a[4], b[4];
      const int cb = ks * 64 + lgrp * 16;
#pragma unroll
      for (int f = 0; f < 4; ++f) {
        a[f] = *(const bf16x8*)((const char*)As + swzb((wr + f * 16 + lrow) * 128 + cb));
        b[f] = *(const bf16x8*)((const char*)Bs + swzb((wc + f * 16 + lrow) * 128 + cb));
      }
#pragma unroll
      for (int mf = 0; mf < 4; ++mf)
#pragma unroll
        for (int nf = 0; nf < 4; ++nf)
          acc[mf][nf] = MFMA(a[mf], b[nf], acc[mf][nf]);
    }
  }

#pragma unroll
  for (int mf = 0; mf < 4; ++mf)
#pragma unroll
    for (int nf = 0; nf < 4; ++nf) {
      const int n = n0 + wc + nf * 16 + lrow;
      const int row0 = m0 + wr + mf * 16 + lgrp * 4;
#pragma unroll
      for (int r = 0; r < 4; ++r)
        y[(size_t)(row0 + r) * 1024 + n] = acc[mf][nf][r];
    }
}

// ---------------------------------------------------------------------------
extern "C" void kernel_launch(void* const* d_in, const int* in_sizes, int n_in,
                              void* d_out, int out_size, void* d_ws, size_t ws_size,
                              hipStream_t stream) {
  const float* x  = (const float*)d_in[0];
  const float* Pq = (const float*)d_in[1];
  const float* Pk = (const float*)d_in[2];
  const float* Pv = (const float*)d_in[3];
  const float* Po = (const float*)d_in[4];
  float* y = (float*)d_out;

  short* ws = (short*)d_ws;
  const size_t NX = (size_t)B_ * M_ * D_;        // 8,388,608
  short* xb  = ws;                 ws += NX;
  short* Wt  = ws;                 ws += (size_t)3072 * 1024;
  short* Wo  = ws;                 ws += (size_t)1024 * 1024;
  short* Qw  = ws;                 ws += NX;
  short* Kw  = ws;                 ws += NX;
  short* Vt  = ws;                 ws += NX;
  short* O2  = ws;                 ws += NX;

  convert_x_kernel <<<4096, 256, 0, stream>>>(x, xb);
  convert_w_kernel <<<3072, 256, 0, stream>>>(Pq, Pk, Pv, Wt);
  convert_wo_kernel<<<1024, 256, 0, stream>>>(Po, Wo);
  qkv_gemm_kernel  <<<1536, 256, 0, stream>>>(xb, Wt, Qw, Kw, Vt);
  attn_kernel      <<<512,  256, 0, stream>>>(Qw, Kw, Vt, O2);
  out_gemm_kernel  <<<512,  256, 0, stream>>>(O2, Wo, y);
}

// Round 3
// 223.135 us; speedup vs baseline: 10.0925x; 2.3106x over previous
//
#include <hip/hip_runtime.h>
#include <hip/hip_bf16.h>

// B=4, M=2048, D=1024, H=16, K=V=64
#define B_  4
#define M_  2048
#define D_  1024
#define H_  16

typedef __attribute__((ext_vector_type(8)))  short bf16x8;
typedef __attribute__((ext_vector_type(4)))  float f32x4;
typedef __attribute__((ext_vector_type(16))) float f32x16;
typedef __attribute__((ext_vector_type(4)))  unsigned short u16x4;
typedef __attribute__((ext_vector_type(2)))  unsigned int uint2v;

#define MFMA16(a, b, c) __builtin_amdgcn_mfma_f32_16x16x32_bf16((a), (b), (c), 0, 0, 0)
#define MFMA32(a, b, c) __builtin_amdgcn_mfma_f32_32x32x16_bf16((a), (b), (c), 0, 0, 0)

// Q pre-scale: 1/sqrt(64) * log2(e)  (softmax done in exp2 domain)
#define QSCALE 0.18033688011112042f

__device__ __forceinline__ unsigned short f2b(float f) {
  union { float f; unsigned u; } v; v.f = f;
  unsigned r = v.u + 0x7FFF + ((v.u >> 16) & 1);   // RNE
  return (unsigned short)(r >> 16);
}

__device__ __forceinline__ unsigned cvtpk(float lo, float hi) {
  unsigned r;
  asm("v_cvt_pk_bf16_f32 %0, %1, %2" : "=v"(r) : "v"(lo), "v"(hi));
  return r;
}

// XOR swizzle within [rows][64-bf16] tiles (128B rows).
__device__ __forceinline__ int swzb(int byte) {
  return byte ^ (((byte >> 7) & 7) << 4);
}

#define GLOAD16(gsrc, ldst)                                                     \
  __builtin_amdgcn_global_load_lds(                                             \
      (const __attribute__((address_space(1))) void*)(gsrc),                    \
      (__attribute__((address_space(3))) void*)(ldst), 16, 0, 0)

// ---------------------------------------------------------------------------
// Conversions
// ---------------------------------------------------------------------------
__global__ __launch_bounds__(256) void convert_x_kernel(
    const float* __restrict__ x, short* __restrict__ xb) {
  const size_t i = ((size_t)blockIdx.x * 256 + threadIdx.x) * 8;
  float4 a = *(const float4*)(x + i);
  float4 b = *(const float4*)(x + i + 4);
  bf16x8 o;
  o[0] = (short)f2b(a.x); o[1] = (short)f2b(a.y); o[2] = (short)f2b(a.z); o[3] = (short)f2b(a.w);
  o[4] = (short)f2b(b.x); o[5] = (short)f2b(b.y); o[6] = (short)f2b(b.z); o[7] = (short)f2b(b.w);
  *(bf16x8*)(xb + i) = o;
}

// Wt[n][d], n = which*1024 + h*64 + kc ; Wt[n][d] = P_which[h][d][kc]
__global__ __launch_bounds__(256) void convert_w_kernel(
    const float* __restrict__ Pq, const float* __restrict__ Pk,
    const float* __restrict__ Pv, short* __restrict__ Wt) {
  const int idx = blockIdx.x * 256 + threadIdx.x;   // n*256 + d/4
  const int n = idx >> 8, d0 = (idx & 255) * 4;
  const int which = n >> 10, h = (n >> 6) & 15, kc = n & 63;
  const float* P = (which == 0) ? Pq : (which == 1) ? Pk : Pv;
  const float* p = P + ((size_t)h * D_ + d0) * 64 + kc;
  u16x4 o;
  o[0] = f2b(p[0]); o[1] = f2b(p[64]); o[2] = f2b(p[128]); o[3] = f2b(p[192]);
  *(u16x4*)(Wt + (size_t)n * D_ + d0) = o;
}

// Wo[d][h*64+v] = P_o[h][d][v]
__global__ __launch_bounds__(256) void convert_wo_kernel(
    const float* __restrict__ Po, short* __restrict__ Wo) {
  const int idx = blockIdx.x * 256 + threadIdx.x;   // d*256 + hv/4
  const int d = idx >> 8, hv0 = (idx & 255) * 4;
  const int h = hv0 >> 6, v = hv0 & 63;
  float4 a = *(const float4*)(Po + ((size_t)h * D_ + d) * 64 + v);
  u16x4 o;
  o[0] = f2b(a.x); o[1] = f2b(a.y); o[2] = f2b(a.z); o[3] = f2b(a.w);
  *(u16x4*)(Wo + (size_t)d * 1024 + hv0) = o;
}

// ---------------------------------------------------------------------------
// QKV projection GEMM: C[8192][3072] = xb[8192][1024] @ Wt[3072][1024]^T
// Epilogue scatters into Qw/Kw [bh][m][64] and Vt [bh][v][m]; Q scaled QSCALE.
// ---------------------------------------------------------------------------
__global__ __launch_bounds__(256) void qkv_gemm_kernel(
    const short* __restrict__ xb, const short* __restrict__ Wt,
    short* __restrict__ Qw, short* __restrict__ Kw, short* __restrict__ Vt) {
  __shared__ short As[128 * 64];
  __shared__ short Bs[128 * 64];
  int bid = blockIdx.x;
  bid = (bid & 7) * 192 + (bid >> 3);            // XCD swizzle (1536 % 8 == 0)
  const int mt = bid & 63, nt = bid >> 6;
  const int m0 = mt * 128, n0 = nt * 128;
  const int t = threadIdx.x, lane = t & 63, w = t >> 6;
  const int wr = (w >> 1) * 64, wc = (w & 1) * 64;
  const int lrow = lane & 15, lgrp = lane >> 4;

  f32x4 acc[4][4] = {};
  const char* Agc = (const char*)xb + (size_t)m0 * D_ * 2;
  const char* Bgc = (const char*)Wt + (size_t)n0 * D_ * 2;

  for (int d0 = 0; d0 < D_; d0 += 64) {
    __syncthreads();
#pragma unroll
    for (int i = 0; i < 4; ++i) {
      const int L = i * 4096 + t * 16;
      const int row = L >> 7;
      const int cb = (L & 127) ^ ((row & 7) << 4);
      GLOAD16(Agc + ((size_t)row * D_ + d0) * 2 + cb, (char*)As + i * 4096 + w * 1024);
      GLOAD16(Bgc + ((size_t)row * D_ + d0) * 2 + cb, (char*)Bs + i * 4096 + w * 1024);
    }
    __syncthreads();
#pragma unroll
    for (int ks = 0; ks < 2; ++ks) {
      bf16x8 a[4], b[4];
      const int cb = ks * 64 + lgrp * 16;
#pragma unroll
      for (int f = 0; f < 4; ++f) {
        a[f] = *(const bf16x8*)((const char*)As + swzb((wr + f * 16 + lrow) * 128 + cb));
        b[f] = *(const bf16x8*)((const char*)Bs + swzb((wc + f * 16 + lrow) * 128 + cb));
      }
#pragma unroll
      for (int mf = 0; mf < 4; ++mf)
#pragma unroll
        for (int nf = 0; nf < 4; ++nf)
          acc[mf][nf] = MFMA16(a[mf], b[nf], acc[mf][nf]);
    }
  }

#pragma unroll
  for (int nf = 0; nf < 4; ++nf) {
    const int n = n0 + wc + nf * 16 + lrow;
    const int which = n >> 10, h = (n >> 6) & 15, kc = n & 63;
#pragma unroll
    for (int mf = 0; mf < 4; ++mf) {
      const int row0 = m0 + wr + mf * 16 + lgrp * 4;
      const int b = row0 >> 11, mm = row0 & 2047;
      const int bh = b * 16 + h;
      if (which == 2) {
        u16x4 o;
        o[0] = f2b(acc[mf][nf][0]); o[1] = f2b(acc[mf][nf][1]);
        o[2] = f2b(acc[mf][nf][2]); o[3] = f2b(acc[mf][nf][3]);
        *(u16x4*)(Vt + ((size_t)bh * 64 + kc) * M_ + mm) = o;
      } else {
        short* outp = (which == 0 ? Qw : Kw) + ((size_t)bh * M_ + mm) * 64 + kc;
        const float scale = (which == 0) ? QSCALE : 1.0f;
#pragma unroll
        for (int r = 0; r < 4; ++r)
          outp[(size_t)r * 64] = (short)f2b(acc[mf][nf][r] * scale);
      }
    }
  }
}

// ---------------------------------------------------------------------------
// Flash attention, swapped-operand 32x32x16 MFMA (m214/T12 structure, D=64).
// Block = 4 waves x 32 q-rows = 128 q-rows. KV tile = 64.
// S^T = K·Q^T  -> lane owns softmax row (q = lane&31) in 32 f32 regs.
// P->bf16 in-register via cvt_pk + permlane32_swap; O^T = V^T·P.
// Grid = 1024: 16 q-chunks per bh, heavy-first, 8 bh per XCD.
// ---------------------------------------------------------------------------
__global__ __launch_bounds__(256) void attn_kernel(
    const short* __restrict__ Qw, const short* __restrict__ Kw,
    const short* __restrict__ Vt, short* __restrict__ O2) {
  __shared__ short Ks[64 * 64];
  __shared__ short Vs[64 * 64];

  const int bid = blockIdx.x;                 // 1024 blocks
  const int xcd = bid & 7, slot = bid >> 3;   // slot 0..127
  const int bh = xcd * 8 + (slot >> 4);       // 8 bh per XCD (KV panel L2-resident)
  const int chunk = 15 - (slot & 15);         // heavy-first (LPT)
  const int q0 = chunk * 128;

  const int t = threadIdx.x, lane = t & 63, w = t >> 6;
  const int qw0 = q0 + w * 32;                // this wave's 32 q-rows
  const int l31 = lane & 31, hi = lane >> 5;
  const int qabs = qw0 + l31;

  // Q B-frags in registers: qfrag[kc] holds Q[q=l31][d=16*kc + 8*hi + e]
  bf16x8 qfrag[4];
#pragma unroll
  for (int kc = 0; kc < 4; ++kc)
    qfrag[kc] = *(const bf16x8*)(Qw + ((size_t)bh * M_ + qabs) * 64 + kc * 16 + hi * 8);

  f32x16 o0 = {}, o1 = {};                    // O^T accum: v-blocks 0,1
  float mrun = -3.0e38f, lrun = 0.f;

  const char* Kg = (const char*)Kw + (size_t)bh * M_ * 128;
  const char* Vg = (const char*)Vt + (size_t)bh * 64 * M_ * 2;

  const int jend = q0 + 128;
  for (int j0 = 0; j0 < jend; j0 += 64) {
    __syncthreads();                           // all waves done reading prev tiles
#pragma unroll
    for (int i = 0; i < 2; ++i) {
      const int L = i * 4096 + t * 16;
      const int row = L >> 7;
      const int cb = (L & 127) ^ ((row & 7) << 4);
      GLOAD16(Kg + (size_t)(j0 + row) * 128 + cb, (char*)Ks + i * 4096 + w * 1024);
      GLOAD16(Vg + (size_t)row * (M_ * 2) + j0 * 2 + cb, (char*)Vs + i * 4096 + w * 1024);
    }
    __syncthreads();                           // staged (drains vmcnt)
    if (j0 >= qw0 + 32) continue;              // fully masked for this wave

    // ---- S^T = K · Q^T : s[mf] covers keys j0+32*mf .. +31, cols q ----
    f32x16 s[2];
#pragma unroll
    for (int mf = 0; mf < 2; ++mf) {
      f32x16 sa = {};
#pragma unroll
      for (int kc = 0; kc < 4; ++kc) {
        bf16x8 kf = *(const bf16x8*)((const char*)Ks +
                      swzb((mf * 32 + l31) * 128 + kc * 32 + hi * 16));
        sa = MFMA32(kf, qfrag[kc], sa);
      }
      s[mf] = sa;
    }

    // ---- causal mask (at most one partial tile per wave) ----
    if (j0 + 64 > qw0) {
#pragma unroll
      for (int mf = 0; mf < 2; ++mf)
#pragma unroll
        for (int r = 0; r < 16; ++r) {
          const int kabs = j0 + mf * 32 + (r & 3) + 8 * (r >> 2) + 4 * hi;
          if (kabs > qabs) s[mf][r] = -3.0e38f;
        }
    }

    // ---- online softmax: lane owns row q, 32 values + partner's 32 ----
    float tm[16];
#pragma unroll
    for (int r = 0; r < 16; ++r) tm[r] = fmaxf(s[0][r], s[1][r]);
#pragma unroll
    for (int st = 8; st > 0; st >>= 1)
#pragma unroll
      for (int r = 0; r < 8; ++r)
        if (r < st) tm[r] = fmaxf(tm[r], tm[r + st]);
    uint2v pm = __builtin_amdgcn_permlane32_swap(
        __float_as_uint(tm[0]), __float_as_uint(tm[0]), false, false);
    const float mtile = fmaxf(__uint_as_float(pm[0]), __uint_as_float(pm[1]));
    const float mnew = fmaxf(mrun, mtile);
    const float alpha = __builtin_amdgcn_exp2f(mrun - mnew);
    mrun = mnew;

#pragma unroll
    for (int mf = 0; mf < 2; ++mf)
#pragma unroll
      for (int r = 0; r < 16; ++r)
        s[mf][r] = __builtin_amdgcn_exp2f(s[mf][r] - mnew);

    float ts[16];
#pragma unroll
    for (int r = 0; r < 16; ++r) ts[r] = s[0][r] + s[1][r];
#pragma unroll
    for (int st = 8; st > 0; st >>= 1)
#pragma unroll
      for (int r = 0; r < 8; ++r)
        if (r < st) ts[r] += ts[r + st];
    uint2v ps = __builtin_amdgcn_permlane32_swap(
        __float_as_uint(ts[0]), __float_as_uint(ts[0]), false, false);
    const float rowsum = __uint_as_float(ps[0]) + __uint_as_float(ps[1]);
    lrun = lrun * alpha + rowsum;
    o0 *= alpha;
    o1 *= alpha;

    // ---- P -> bf16 PV B-operand frags, fully in-register ----
    // chunk c covers keys 16c..16c+15: lane holds P[q=l31][key=16c+8*hi+e]
    bf16x8 pfrag[4];
#pragma unroll
    for (int c = 0; c < 4; ++c) {
      const int mf = c >> 1, rb = (c & 1) * 8;
      unsigned a0 = cvtpk(s[mf][rb + 0], s[mf][rb + 1]);
      unsigned a1 = cvtpk(s[mf][rb + 2], s[mf][rb + 3]);
      unsigned b0 = cvtpk(s[mf][rb + 4], s[mf][rb + 5]);
      unsigned b1 = cvtpk(s[mf][rb + 6], s[mf][rb + 7]);
      uint2v s0 = __builtin_amdgcn_permlane32_swap(a0, b0, false, false);
      uint2v s1 = __builtin_amdgcn_permlane32_swap(a1, b1, false, false);
      union { unsigned u[4]; bf16x8 v; } pk;
      pk.u[0] = s0[0]; pk.u[1] = s1[0]; pk.u[2] = s0[1]; pk.u[3] = s1[1];
      pfrag[c] = pk.v;
    }

    // ---- O^T += V^T · P ----
#pragma unroll
    for (int c = 0; c < 4; ++c) {
      bf16x8 v0 = *(const bf16x8*)((const char*)Vs +
                    swzb((l31) * 128 + c * 32 + hi * 16));
      bf16x8 v1 = *(const bf16x8*)((const char*)Vs +
                    swzb((32 + l31) * 128 + c * 32 + hi * 16));
      o0 = MFMA32(v0, pfrag[c], o0);
      o1 = MFMA32(v1, pfrag[c], o1);
    }
  }

  // ---- epilogue: O2[b][m=qabs][h*64 + v] = O^T / l ----
  const int b = bh >> 4, h = bh & 15;
  const float inv = 1.0f / lrun;
  short* orow = O2 + ((size_t)b * M_ + qabs) * 1024 + h * 64;
#pragma unroll
  for (int vb = 0; vb < 2; ++vb) {
    const f32x16& o = vb ? o1 : o0;
#pragma unroll
    for (int g = 0; g < 4; ++g) {
      const int vbase = vb * 32 + 8 * g + 4 * hi;
      u16x4 pkt;
      pkt[0] = f2b(o[g * 4 + 0] * inv);
      pkt[1] = f2b(o[g * 4 + 1] * inv);
      pkt[2] = f2b(o[g * 4 + 2] * inv);
      pkt[3] = f2b(o[g * 4 + 3] * inv);
      *(u16x4*)(orow + vbase) = pkt;
    }
  }
}

// ---------------------------------------------------------------------------
// Output projection: y[8192][1024] = O2[8192][1024](bf16) @ Wo[1024][1024]^T
// ---------------------------------------------------------------------------
__global__ __launch_bounds__(256) void out_gemm_kernel(
    const short* __restrict__ O2, const short* __restrict__ Wo,
    float* __restrict__ y) {
  __shared__ short As[128 * 64];
  __shared__ short Bs[128 * 64];
  int bid = blockIdx.x;
  bid = (bid & 7) * 64 + (bid >> 3);        // XCD swizzle (512 % 8 == 0)
  const int mt = bid & 63, nt = bid >> 6;
  const int m0 = mt * 128, n0 = nt * 128;
  const int t = threadIdx.x, lane = t & 63, w = t >> 6;
  const int wr = (w >> 1) * 64, wc = (w & 1) * 64;
  const int lrow = lane & 15, lgrp = lane >> 4;

  f32x4 acc[4][4] = {};
  const char* Agc = (const char*)O2 + (size_t)m0 * 1024 * 2;
  const char* Bgc = (const char*)Wo + (size_t)n0 * 1024 * 2;

  for (int d0 = 0; d0 < 1024; d0 += 64) {
    __syncthreads();
#pragma unroll
    for (int i = 0; i < 4; ++i) {
      const int L = i * 4096 + t * 16;
      const int row = L >> 7;
      const int cb = (L & 127) ^ ((row & 7) << 4);
      GLOAD16(Agc + ((size_t)row * 1024 + d0) * 2 + cb, (char*)As + i * 4096 + w * 1024);
      GLOAD16(Bgc + ((size_t)row * 1024 + d0) * 2 + cb, (char*)Bs + i * 4096 + w * 1024);
    }
    __syncthreads();
#pragma unroll
    for (int ks = 0; ks < 2; ++ks) {
      bf16x8 a[4], b[4];
      const int cb = ks * 64 + lgrp * 16;
#pragma unroll
      for (int f = 0; f < 4; ++f) {
        a[f] = *(const bf16x8*)((const char*)As + swzb((wr + f * 16 + lrow) * 128 + cb));
        b[f] = *(const bf16x8*)((const char*)Bs + swzb((wc + f * 16 + lrow) * 128 + cb));
      }
#pragma unroll
      for (int mf = 0; mf < 4; ++mf)
#pragma unroll
        for (int nf = 0; nf < 4; ++nf)
          acc[mf][nf] = MFMA16(a[mf], b[nf], acc[mf][nf]);
    }
  }

#pragma unroll
  for (int mf = 0; mf < 4; ++mf)
#pragma unroll
    for (int nf = 0; nf < 4; ++nf) {
      const int n = n0 + wc + nf * 16 + lrow;
      const int row0 = m0 + wr + mf * 16 + lgrp * 4;
#pragma unroll
      for (int r = 0; r < 4; ++r)
        y[(size_t)(row0 + r) * 1024 + n] = acc[mf][nf][r];
    }
}

// ---------------------------------------------------------------------------
extern "C" void kernel_launch(void* const* d_in, const int* in_sizes, int n_in,
                              void* d_out, int out_size, void* d_ws, size_t ws_size,
                              hipStream_t stream) {
  const float* x  = (const float*)d_in[0];
  const float* Pq = (const float*)d_in[1];
  const float* Pk = (const float*)d_in[2];
  const float* Pv = (const float*)d_in[3];
  const float* Po = (const float*)d_in[4];
  float* y = (float*)d_out;

  short* ws = (short*)d_ws;
  const size_t NX = (size_t)B_ * M_ * D_;        // 8,388,608
  short* xb  = ws;                 ws += NX;
  short* Wt  = ws;                 ws += (size_t)3072 * 1024;
  short* Wo  = ws;                 ws += (size_t)1024 * 1024;
  short* Qw  = ws;                 ws += NX;
  short* Kw  = ws;                 ws += NX;
  short* Vt  = ws;                 ws += NX;
  short* O2  = ws;                 ws += NX;

  convert_x_kernel <<<4096, 256, 0, stream>>>(x, xb);
  convert_w_kernel <<<3072, 256, 0, stream>>>(Pq, Pk, Pv, Wt);
  convert_wo_kernel<<<1024, 256, 0, stream>>>(Po, Wo);
  qkv_gemm_kernel  <<<1536, 256, 0, stream>>>(xb, Wt, Qw, Kw, Vt);
  attn_kernel      <<<1024, 256, 0, stream>>>(Qw, Kw, Vt, O2);
  out_gemm_kernel  <<<512,  256, 0, stream>>>(O2, Wo, y);
}